// Round 10
// baseline (1077.693 us; speedup 1.0000x reference)
//
#include <hip/hip_runtime.h>
#include <cstdint>
#include <cstddef>

#define NB 8
#define NS 1024
#define NE 512
#define NH 8
#define ND 64
#define NL 6
#define NHF 2048
#define NROW (NB*NS)   // 8192

typedef __bf16 bf16_t;
typedef __bf16 bf8v __attribute__((ext_vector_type(8)));
typedef __bf16 bf4v __attribute__((ext_vector_type(4)));
typedef float  f4   __attribute__((ext_vector_type(4)));

extern "C" __device__ float __ocml_native_exp2_f32(float);
#define EXP2F __ocml_native_exp2_f32
#define LOG2E 1.4426950408889634f

// ---- async global->LDS, 16B per lane (LDS dest = wave-uniform base + lane*16) ----
__device__ __forceinline__ void async_copy16(const bf16_t* g, bf16_t* l) {
    __builtin_amdgcn_global_load_lds(
        (const __attribute__((address_space(1))) void*)g,
        (__attribute__((address_space(3))) void*)l,
        16, 0, 0);
}

// gelu(x) = x * sigmoid(2*0.7978845608*(x+0.044715x^3)); exp2-domain, v_rcp.
__device__ __forceinline__ float gelu_f(float x) {
    const float s = fmaf(0.044715f * x * x, x, x);
    const float e = EXP2F(-2.3022081995f * s);   // 2*0.7978845608*log2(e)
    return x * __builtin_amdgcn_rcpf(1.0f + e);
}

// ---------------------------------------------------------------------------
// Core bf16 GEMM: C[M,N] = A[M,K] * B[N,K]^T (+bias, opt gelu)
// OUT: 1 = bf16 row-major, 2 = fp32 in-place residual add (R += acc+bias),
//      3 = bf16 scattered into Vt[(b*8+h)*64+d][s] layout.
// OUT 1/2 use SWAPPED mfma (D^T): lane owns 4 consecutive n -> 8B stores /
// float4 residual RMW. OUT 3 natural order (4 consecutive s -> 8B store).
// 128xBN tile, BK=64, 256 threads, XOR-8 LDS swizzle (conflict-free).
// A and B staged via global_load_lds, DOUBLE-BUFFERED, one barrier/k-iter.
// ---------------------------------------------------------------------------
template<int BN, int ACT, int OUT>
__device__ __forceinline__ void gemm_core(
    bf16_t* __restrict__ sm,
    const bf16_t* __restrict__ A, const bf16_t* __restrict__ Bm,
    const float* __restrict__ bias, float* __restrict__ R, bf16_t* __restrict__ Cb,
    int m0, int n0, int N, int K)
{
    constexpr int JN = BN / 32, WSPAN = BN / 2;
    bf16_t* As = sm;             // 2 x 8192
    bf16_t* Bs = sm + 2*128*64;  // 2 x (BN*64)
    const int tid  = threadIdx.x;
    const int lane = tid & 63;
    const int wave = tid >> 6;
    const int wm = wave >> 1, wn = wave & 1;
    const int quad = lane >> 4, l16 = lane & 15;
    const int srow = tid >> 3;                         // 0..31
    const int scol = (((tid & 7) ^ (srow & 7)) << 3);  // swizzled source col

    f4 acc[4][JN] = {};

    const bf16_t* Ag = A  + (size_t)(m0 + srow) * K + scol;
    const bf16_t* Bg = Bm + (size_t)(n0 + srow) * K + scol;
    const int sw = (l16 & 7);

    auto stage = [&](int buf, int kt) {
#pragma unroll
        for (int r = 0; r < 4; ++r)
            async_copy16(Ag + (size_t)r * 32 * K + kt, As + buf*8192 + tid*8 + r*2048);
#pragma unroll
        for (int r = 0; r < BN/32; ++r)
            async_copy16(Bg + (size_t)r * 32 * K + kt, Bs + buf*(BN*64) + tid*8 + r*2048);
    };

    stage(0, 0);
    int buf = 0;
    for (int kt = 0; kt < K; kt += 64, buf ^= 1) {
        __syncthreads();                       // drains buf's loads; frees buf^1
        if (kt + 64 < K) stage(buf ^ 1, kt + 64);
        const bf16_t* Ab = As + buf*8192;
        const bf16_t* Bb = Bs + buf*(BN*64);
#pragma unroll
        for (int s = 0; s < 2; ++s) {
            const int c8 = ((s*4 + quad) ^ sw) * 8;
            bf8v af[4], bfv[JN];
#pragma unroll
            for (int i = 0; i < 4; ++i)
                af[i] = *(const bf8v*)(Ab + (wm*64 + i*16 + l16)*64 + c8);
#pragma unroll
            for (int j = 0; j < JN; ++j)
                bfv[j] = *(const bf8v*)(Bb + (wn*WSPAN + j*16 + l16)*64 + c8);
#pragma unroll
            for (int i = 0; i < 4; ++i)
#pragma unroll
                for (int j = 0; j < JN; ++j) {
                    if (OUT == 3)
                        acc[i][j] = __builtin_amdgcn_mfma_f32_16x16x32_bf16(af[i], bfv[j], acc[i][j], 0, 0, 0);
                    else
                        acc[i][j] = __builtin_amdgcn_mfma_f32_16x16x32_bf16(bfv[j], af[i], acc[i][j], 0, 0, 0);
                }
        }
    }

    if (OUT != 3) {
        // swapped layout: m = ...+l16, n = ...+quad*4+r (4 consecutive n/lane)
#pragma unroll
        for (int i = 0; i < 4; ++i) {
            const size_t m = (size_t)(m0 + wm*64 + i*16 + l16);
#pragma unroll
            for (int j = 0; j < JN; ++j) {
                const int nb = n0 + wn*WSPAN + j*16 + quad*4;
                const f4 bv = *(const f4*)(bias + nb);
                f4 v = acc[i][j] + bv;
                if (ACT) {
#pragma unroll
                    for (int r = 0; r < 4; ++r) v[r] = gelu_f(v[r]);
                }
                if (OUT == 1) {
                    bf4v o;
#pragma unroll
                    for (int r = 0; r < 4; ++r) o[r] = (bf16_t)v[r];
                    *(bf4v*)(Cb + m * (size_t)N + nb) = o;
                } else {
                    f4* rp = (f4*)(R + m * (size_t)N + nb);
                    *rp = *rp + v;
                }
            }
        }
    } else {
        // natural layout: m = ...+quad*4+r (4 consecutive s in Vt), n = ...+l16
#pragma unroll
        for (int j = 0; j < JN; ++j) {
            const int n = n0 + wn*WSPAN + j*16 + l16;
            const float bv = bias[n];
#pragma unroll
            for (int i = 0; i < 4; ++i) {
                const int mbase = m0 + wm*64 + i*16 + quad*4;
                bf4v o;
#pragma unroll
                for (int r = 0; r < 4; ++r) o[r] = (bf16_t)(acc[i][j][r] + bv);
                const size_t b8h = (size_t)((mbase >> 10)*8 + (n >> 6));
                *(bf4v*)(Cb + (b8h*64 + (size_t)(n & 63))*1024 + (mbase & 1023)) = o;
            }
        }
    }
}

template<int BN, int ACT, int OUT>
__global__ __launch_bounds__(256)
void gemm_bt_k(const bf16_t* __restrict__ A, const bf16_t* __restrict__ Bm,
               const float* __restrict__ bias, float* __restrict__ R,
               bf16_t* __restrict__ Cb, int N, int K)
{
    __shared__ __align__(16) bf16_t smem[2*128*64 + 2*BN*64];
    gemm_core<BN, ACT, OUT>(smem, A, Bm, bias, R, Cb, blockIdx.x * 128, blockIdx.y * BN, N, K);
}

// fused QKV: gridDim.y = 12 (3 mats x 4 n-blocks of 128; V goes to Vt layout).
__global__ __launch_bounds__(256)
void gemm_qkv_k(const bf16_t* __restrict__ A,
                const bf16_t* __restrict__ wq, const bf16_t* __restrict__ wk, const bf16_t* __restrict__ wv,
                const float* __restrict__ bq, const float* __restrict__ bk, const float* __restrict__ bv,
                bf16_t* __restrict__ Q, bf16_t* __restrict__ K, bf16_t* __restrict__ Vt)
{
    __shared__ __align__(16) bf16_t smem[2*128*64 + 2*128*64];
    const int mat = blockIdx.y >> 2;
    const int m0 = blockIdx.x * 128, n0 = (blockIdx.y & 3) * 128;
    if (mat == 0)      gemm_core<128, 0, 1>(smem, A, wq, bq, nullptr, Q,  m0, n0, NE, NE);
    else if (mat == 1) gemm_core<128, 0, 1>(smem, A, wk, bk, nullptr, K,  m0, n0, NE, NE);
    else               gemm_core<128, 0, 3>(smem, A, wv, bv, nullptr, Vt, m0, n0, NE, NE);
}

// ---------------------------------------------------------------------------
// Flash attention: one block = one (b,h) x 128 q-rows, TWO waves x 64 q each
// (qi=4). Halves the K/V LDS-read duplication vs 4 waves (the binding pipe):
// per block-tile kf16+vf16+pf16 reads + 16KB P-writes = 64 KB (was 96 KB).
// K-tile = 64 keys, double-buffered, one barrier/iter. No running max
// (scores O(1); masked keys underflow exp2 to 0). grid (64 bh, 8 qb):
// q-blocks of one bh share an XCD for K/V L2 reuse. LDS 48KB, block=128.
// ---------------------------------------------------------------------------
__global__ __launch_bounds__(128)
void attn_k(const bf16_t* __restrict__ Q, const bf16_t* __restrict__ Kg,
            const bf16_t* __restrict__ Vt, const float* __restrict__ maskf,
            bf16_t* __restrict__ O)
{
    __shared__ __align__(16) bf16_t Ks[2][64*64];  // [key][d]  swizzled
    __shared__ __align__(16) bf16_t Vs[2][64*64];  // [d][key]  swizzled
    __shared__ __align__(16) bf16_t Ps[2][64*64];  // per-wave P, swizzled
    const int tid  = threadIdx.x;
    const int lane = tid & 63;
    const int wave = tid >> 6;                     // 0..1
    const int quad = lane >> 4, l16 = lane & 15;
    const int sw = l16 & 7;
    const int bh = blockIdx.x;
    const int b = bh >> 3, h = bh & 7;
    const int q0 = blockIdx.y * 128;

    bf8v qf[4][2];
#pragma unroll
    for (int qi = 0; qi < 4; ++qi) {
        const bf16_t* Qp = Q + (size_t)(b*NS + q0 + wave*64 + qi*16 + l16) * NE + h*ND;
        qf[qi][0] = *(const bf8v*)(Qp + quad*8);
        qf[qi][1] = *(const bf8v*)(Qp + 32 + quad*8);
    }

    f4 oacc[4][4] = {};
    float rs[4] = {0.f, 0.f, 0.f, 0.f};

    const int srow = tid >> 3;                         // 0..15
    const int scol = (((tid & 7) ^ (srow & 7)) << 3);  // swizzled source col
    const float c1 = 0.125f * LOG2E;

    auto stage = [&](int buf, int kt) {
#pragma unroll
        for (int r = 0; r < 4; ++r) {
            async_copy16(Kg + (size_t)(b*NS + kt + r*16 + srow) * NE + h*ND + scol,
                         Ks[buf] + (r*128 + tid) * 8);
            async_copy16(Vt + (size_t)(bh*ND + r*16 + srow) * NS + kt + scol,
                         Vs[buf] + (r*128 + tid) * 8);
        }
    };

    stage(0, 0);
    int buf = 0;
    for (int kt = 0; kt < NS; kt += 64, buf ^= 1) {
        __syncthreads();
        if (kt + 64 < NS) stage(buf ^ 1, kt + 64);

        // S = Q*K^T (swapped): sacc[qi][j][r] = S[q=...+l16][key=j*16+quad*4+r]
        f4 sacc[4][4] = {};
#pragma unroll
        for (int j = 0; j < 4; ++j) {
            bf8v kf0 = *(const bf8v*)(Ks[buf] + (j*16 + l16)*64 + ((quad    ) ^ sw)*8);
            bf8v kf1 = *(const bf8v*)(Ks[buf] + (j*16 + l16)*64 + ((quad + 4) ^ sw)*8);
#pragma unroll
            for (int qi = 0; qi < 4; ++qi) {
                sacc[qi][j] = __builtin_amdgcn_mfma_f32_16x16x32_bf16(kf0, qf[qi][0], sacc[qi][j], 0, 0, 0);
                sacc[qi][j] = __builtin_amdgcn_mfma_f32_16x16x32_bf16(kf1, qf[qi][1], sacc[qi][j], 0, 0, 0);
            }
        }

        // P = exp2(S*c1 + mask); packed 8B writes to per-wave LDS (A-layout)
        bf16_t* Pw = Ps[wave];
#pragma unroll
        for (int j = 0; j < 4; ++j) {
            const f4 mkv = *(const f4*)(maskf + b*NS + kt + j*16 + quad*4);
#pragma unroll
            for (int qi = 0; qi < 4; ++qi) {
                bf4v o;
#pragma unroll
                for (int r = 0; r < 4; ++r) {
                    const float p = EXP2F(fmaf(sacc[qi][j][r], c1, mkv[r]));
                    rs[qi] += p;
                    o[r] = (bf16_t)p;
                }
                const int row = qi*16 + l16;
                const int chunk = (j*2 + (quad >> 1)) ^ sw;
                *(bf4v*)(Pw + row*64 + chunk*8 + (quad & 1)*4) = o;
            }
        }

        // O += P*V (swapped): oacc[qi][nt][r] = O[q=l16][d=nt*16+quad*4+r]
#pragma unroll
        for (int ks = 0; ks < 2; ++ks) {
            bf8v pf[4];
#pragma unroll
            for (int qi = 0; qi < 4; ++qi)
                pf[qi] = *(const bf8v*)(Pw + (qi*16 + l16)*64 + ((ks*4 + quad) ^ sw)*8);
#pragma unroll
            for (int nt = 0; nt < 4; ++nt) {
                bf8v vf = *(const bf8v*)(Vs[buf] + (nt*16 + l16)*64 + ((ks*4 + quad) ^ sw)*8);
#pragma unroll
                for (int qi = 0; qi < 4; ++qi)
                    oacc[qi][nt] = __builtin_amdgcn_mfma_f32_16x16x32_bf16(vf, pf[qi], oacc[qi][nt], 0, 0, 0);
            }
        }
    }

    // reduce row sums across quads (scalar per lane), scale, packed stores
#pragma unroll
    for (int qi = 0; qi < 4; ++qi) {
        float s = rs[qi];
        s += __shfl_xor(s, 16, 64);
        s += __shfl_xor(s, 32, 64);
        const float inv = 1.0f / s;
        const size_t row = (size_t)(b*NS + q0 + wave*64 + qi*16 + l16);
#pragma unroll
        for (int nt = 0; nt < 4; ++nt) {
            bf4v o;
#pragma unroll
            for (int r = 0; r < 4; ++r) o[r] = (bf16_t)(oacc[qi][nt][r] * inv);
            *(bf4v*)(O + row * NE + h*ND + nt*16 + quad*4) = o;
        }
    }
}

// ---------------------------------------------------------------------------
// LayerNorm over x32 (residual already added by GEMM epilogue).
// Writes bf16 activation AND fp32 LN output (the next residual / d_out).
// ---------------------------------------------------------------------------
__global__ __launch_bounds__(256)
void ln_k(const float* __restrict__ xin,
          const float* __restrict__ gamma, const float* __restrict__ beta,
          bf16_t* __restrict__ xbout, float* __restrict__ fout)
{
    const int row = blockIdx.x;
    const int tid = threadIdx.x;
    const size_t base = (size_t)row * NE;
    const float x0 = xin[base + tid];
    const float x1 = xin[base + tid + 256];
    float s  = x0 + x1;
    float ss = x0*x0 + x1*x1;
#pragma unroll
    for (int off = 32; off > 0; off >>= 1) {
        s  += __shfl_down(s,  off, 64);
        ss += __shfl_down(ss, off, 64);
    }
    __shared__ float red[8];
    const int wave = tid >> 6;
    if ((tid & 63) == 0) { red[wave] = s; red[4 + wave] = ss; }
    __syncthreads();
    s  = red[0] + red[1] + red[2] + red[3];
    ss = red[4] + red[5] + red[6] + red[7];
    const float mean = s * (1.0f / NE);
    const float var  = ss * (1.0f / NE) - mean * mean;
    const float inv  = rsqrtf(var + 1e-5f);
    const float o0 = gamma[tid]       * ((x0 - mean) * inv) + beta[tid];
    const float o1 = gamma[tid + 256] * ((x1 - mean) * inv) + beta[tid + 256];
    xbout[base + tid]       = (bf16_t)o0;
    xbout[base + tid + 256] = (bf16_t)o1;
    fout[base + tid]        = o0;
    fout[base + tid + 256]  = o1;
}

// one-shot fp32->bf16 conversion of all 6 weight tensors + x (single launch)
#define W4SZ ((size_t)NL*NE*NE/4)     // float4s per E x E weight set
#define WBSZ ((size_t)NL*NE*NHF/4)    // float4s per E x HF weight set
#define XSZ  ((size_t)NROW*NE/4)      // float4s for x
#define CVT_TOTAL (4*W4SZ + 2*WBSZ + XSZ)

__global__ void cvt_all(const float* __restrict__ wq, const float* __restrict__ wk,
                        const float* __restrict__ wv, const float* __restrict__ wo,
                        const float* __restrict__ w1, const float* __restrict__ w2,
                        const float* __restrict__ x,
                        bf16_t* __restrict__ owq, bf16_t* __restrict__ owk,
                        bf16_t* __restrict__ owv, bf16_t* __restrict__ owo,
                        bf16_t* __restrict__ ow1, bf16_t* __restrict__ ow2,
                        bf16_t* __restrict__ ox)
{
    size_t i = (size_t)blockIdx.x * 256 + threadIdx.x;
    if (i >= CVT_TOTAL) return;
    const float* src; bf16_t* dst;
    if      (i < 1*W4SZ)           { src = wq; dst = owq; }
    else if (i < 2*W4SZ)           { src = wk; dst = owk; i -= 1*W4SZ; }
    else if (i < 3*W4SZ)           { src = wv; dst = owv; i -= 2*W4SZ; }
    else if (i < 4*W4SZ)           { src = wo; dst = owo; i -= 3*W4SZ; }
    else if (i < 4*W4SZ + WBSZ)    { src = w1; dst = ow1; i -= 4*W4SZ; }
    else if (i < 4*W4SZ + 2*WBSZ)  { src = w2; dst = ow2; i -= 4*W4SZ + WBSZ; }
    else                           { src = x;  dst = ox;  i -= 4*W4SZ + 2*WBSZ; }
    const f4 v = ((const f4*)src)[i];
    bf4v o;
    o[0] = (bf16_t)v[0]; o[1] = (bf16_t)v[1]; o[2] = (bf16_t)v[2]; o[3] = (bf16_t)v[3];
    ((bf4v*)dst)[i] = o;
}

__global__ void make_maskf(const int* __restrict__ m, float* __restrict__ out, int n)
{
    const int i = blockIdx.x * 256 + threadIdx.x;
    if (i < n) out[i] = m[i] ? 0.0f : -1.0e6f * LOG2E;  // exp2-domain mask
}

// ---------------------------------------------------------------------------
extern "C" void kernel_launch(void* const* d_in, const int* in_sizes, int n_in,
                              void* d_out, int out_size, void* d_ws, size_t ws_size,
                              hipStream_t stream)
{
    (void)in_sizes; (void)n_in; (void)out_size; (void)ws_size;
    const float* x   = (const float*)d_in[0];
    const int*   msk = (const int*)d_in[1];
    const float* WQ = (const float*)d_in[2];  const float* bQ  = (const float*)d_in[3];
    const float* WK = (const float*)d_in[4];  const float* bK  = (const float*)d_in[5];
    const float* WV = (const float*)d_in[6];  const float* bV  = (const float*)d_in[7];
    const float* WO = (const float*)d_in[8];  const float* bO  = (const float*)d_in[9];
    const float* W1 = (const float*)d_in[10]; const float* b1  = (const float*)d_in[11];
    const float* W2 = (const float*)d_in[12]; const float* b2  = (const float*)d_in[13];
    const float* g1 = (const float*)d_in[14]; const float* bt1 = (const float*)d_in[15];
    const float* g2 = (const float*)d_in[16]; const float* bt2 = (const float*)d_in[17];

    char* ws = (char*)d_ws;
    size_t off = 0;
    auto alloc = [&](size_t bytes) { char* p = ws + off; off += (bytes + 255) & ~(size_t)255; return p; };
    float*  x32   = (float*) alloc((size_t)NROW*NE*4);
    bf16_t* xb    = (bf16_t*)alloc((size_t)NROW*NE*2);
    bf16_t* Qb    = (bf16_t*)alloc((size_t)NROW*NE*2);
    bf16_t* Kb    = (bf16_t*)alloc((size_t)NROW*NE*2);
    bf16_t* Vtb   = (bf16_t*)alloc((size_t)NROW*NE*2);
    bf16_t* AOb   = (bf16_t*)alloc((size_t)NROW*NE*2);
    bf16_t* hb    = (bf16_t*)alloc((size_t)NROW*NHF*2);
    bf16_t* wqc   = (bf16_t*)alloc((size_t)NL*NE*NE*2);
    bf16_t* wkc   = (bf16_t*)alloc((size_t)NL*NE*NE*2);
    bf16_t* wvc   = (bf16_t*)alloc((size_t)NL*NE*NE*2);
    bf16_t* woc   = (bf16_t*)alloc((size_t)NL*NE*NE*2);
    bf16_t* w1c   = (bf16_t*)alloc((size_t)NL*NHF*NE*2);
    bf16_t* w2c   = (bf16_t*)alloc((size_t)NL*NE*NHF*2);
    float*  maskf = (float*) alloc((size_t)NB*NS*4);

    cvt_all<<<dim3((unsigned)((CVT_TOTAL + 255) / 256)), dim3(256), 0, stream>>>(
        WQ, WK, WV, WO, W1, W2, x, wqc, wkc, wvc, woc, w1c, w2c, xb);
    hipMemcpyAsync(x32, x, (size_t)NROW*NE*4, hipMemcpyDeviceToDevice, stream);
    make_maskf<<<dim3(32), dim3(256), 0, stream>>>(msk, maskf, NB*NS);

    for (int l = 0; l < NL; ++l) {
        const bf16_t* wq  = wqc + (size_t)l*NE*NE;
        const bf16_t* wk  = wkc + (size_t)l*NE*NE;
        const bf16_t* wv  = wvc + (size_t)l*NE*NE;
        const bf16_t* wo  = woc + (size_t)l*NE*NE;
        const bf16_t* w1p = w1c + (size_t)l*NHF*NE;
        const bf16_t* w2p = w2c + (size_t)l*NE*NHF;

        gemm_qkv_k<<<dim3(64, 12), dim3(256), 0, stream>>>(
            xb, wq, wk, wv, bQ + l*NE, bK + l*NE, bV + l*NE, Qb, Kb, Vtb);
        attn_k<<<dim3(64, 8), dim3(128), 0, stream>>>(Qb, Kb, Vtb, maskf, AOb);
        gemm_bt_k<64, 0, 2><<<dim3(64, 8), dim3(256), 0, stream>>>(
            AOb, wo, bO + l*NE, x32, nullptr, NE, NE);
        ln_k<<<dim3(NROW), dim3(256), 0, stream>>>(
            x32, g1 + l*NE, bt1 + l*NE, xb, x32);
        gemm_bt_k<128, 1, 1><<<dim3(64, 16), dim3(256), 0, stream>>>(
            xb, w1p, b1 + l*NHF, nullptr, hb, NHF, NE);
        gemm_bt_k<64, 0, 2><<<dim3(64, 8), dim3(256), 0, stream>>>(
            hb, w2p, b2 + l*NE, x32, nullptr, NE, NHF);
        const int last = (l == NL - 1);
        ln_k<<<dim3(NROW), dim3(256), 0, stream>>>(
            x32, g2 + l*NE, bt2 + l*NE, xb, last ? (float*)d_out : x32);
    }
}

// Round 11
// 967.772 us; speedup vs baseline: 1.1136x; 1.1136x over previous
//
#include <hip/hip_runtime.h>
#include <cstdint>
#include <cstddef>

#define NB 8
#define NS 1024
#define NE 512
#define NH 8
#define ND 64
#define NL 6
#define NHF 2048
#define NROW (NB*NS)   // 8192

typedef __bf16 bf16_t;
typedef __bf16 bf8v __attribute__((ext_vector_type(8)));
typedef __bf16 bf4v __attribute__((ext_vector_type(4)));
typedef float  f4   __attribute__((ext_vector_type(4)));

extern "C" __device__ float __ocml_native_exp2_f32(float);
#define EXP2F __ocml_native_exp2_f32
#define LOG2E 1.4426950408889634f

// ---- async global->LDS, 16B per lane (LDS dest = wave-uniform base + lane*16) ----
__device__ __forceinline__ void async_copy16(const bf16_t* g, bf16_t* l) {
    __builtin_amdgcn_global_load_lds(
        (const __attribute__((address_space(1))) void*)g,
        (__attribute__((address_space(3))) void*)l,
        16, 0, 0);
}

// gelu(x) = x * sigmoid(2*0.7978845608*(x+0.044715x^3)); exp2-domain, v_rcp.
__device__ __forceinline__ float gelu_f(float x) {
    const float s = fmaf(0.044715f * x * x, x, x);
    const float e = EXP2F(-2.3022081995f * s);   // 2*0.7978845608*log2(e)
    return x * __builtin_amdgcn_rcpf(1.0f + e);
}

// ---------------------------------------------------------------------------
// Core bf16 GEMM: C[M,N] = A[M,K] * B[N,K]^T (+bias, opt gelu)
// OUT: 1 = bf16 row-major, 2 = bf16 in-place residual RMW (Cb += acc+bias),
//      3 = bf16 scattered into Vt[(b*8+h)*64+d][s] layout.
// OUT 1/2 use SWAPPED mfma (D^T): lane owns 4 consecutive n -> 8B stores.
// OUT 3 natural order (4 consecutive s -> 8B store).
// 128xBN tile, BK=64, 256 threads, XOR-8 LDS swizzle (conflict-free).
// A and B staged via global_load_lds, DOUBLE-BUFFERED, one barrier/k-iter
// (prefetch issued after the barrier overlaps compute; drained next barrier).
// ---------------------------------------------------------------------------
template<int BN, int ACT, int OUT>
__device__ __forceinline__ void gemm_core(
    bf16_t* __restrict__ sm,
    const bf16_t* __restrict__ A, const bf16_t* __restrict__ Bm,
    const float* __restrict__ bias, bf16_t* __restrict__ Cb,
    int m0, int n0, int N, int K)
{
    constexpr int JN = BN / 32, WSPAN = BN / 2;
    bf16_t* As = sm;             // 2 x 8192
    bf16_t* Bs = sm + 2*128*64;  // 2 x (BN*64)
    const int tid  = threadIdx.x;
    const int lane = tid & 63;
    const int wave = tid >> 6;
    const int wm = wave >> 1, wn = wave & 1;
    const int quad = lane >> 4, l16 = lane & 15;
    const int srow = tid >> 3;                         // 0..31
    const int scol = (((tid & 7) ^ (srow & 7)) << 3);  // swizzled source col

    f4 acc[4][JN] = {};

    const bf16_t* Ag = A  + (size_t)(m0 + srow) * K + scol;
    const bf16_t* Bg = Bm + (size_t)(n0 + srow) * K + scol;
    const int sw = (l16 & 7);

    auto stage = [&](int buf, int kt) {
#pragma unroll
        for (int r = 0; r < 4; ++r)
            async_copy16(Ag + (size_t)r * 32 * K + kt, As + buf*8192 + tid*8 + r*2048);
#pragma unroll
        for (int r = 0; r < BN/32; ++r)
            async_copy16(Bg + (size_t)r * 32 * K + kt, Bs + buf*(BN*64) + tid*8 + r*2048);
    };

    stage(0, 0);
    int buf = 0;
    for (int kt = 0; kt < K; kt += 64, buf ^= 1) {
        __syncthreads();                       // drains buf's loads; frees buf^1
        if (kt + 64 < K) stage(buf ^ 1, kt + 64);
        const bf16_t* Ab = As + buf*8192;
        const bf16_t* Bb = Bs + buf*(BN*64);
#pragma unroll
        for (int s = 0; s < 2; ++s) {
            const int c8 = ((s*4 + quad) ^ sw) * 8;
            bf8v af[4], bfv[JN];
#pragma unroll
            for (int i = 0; i < 4; ++i)
                af[i] = *(const bf8v*)(Ab + (wm*64 + i*16 + l16)*64 + c8);
#pragma unroll
            for (int j = 0; j < JN; ++j)
                bfv[j] = *(const bf8v*)(Bb + (wn*WSPAN + j*16 + l16)*64 + c8);
#pragma unroll
            for (int i = 0; i < 4; ++i)
#pragma unroll
                for (int j = 0; j < JN; ++j) {
                    if (OUT == 3)
                        acc[i][j] = __builtin_amdgcn_mfma_f32_16x16x32_bf16(af[i], bfv[j], acc[i][j], 0, 0, 0);
                    else
                        acc[i][j] = __builtin_amdgcn_mfma_f32_16x16x32_bf16(bfv[j], af[i], acc[i][j], 0, 0, 0);
                }
        }
    }

    if (OUT != 3) {
        // swapped layout: m = ...+l16, n = ...+quad*4+r (4 consecutive n/lane)
#pragma unroll
        for (int i = 0; i < 4; ++i) {
            const size_t m = (size_t)(m0 + wm*64 + i*16 + l16);
#pragma unroll
            for (int j = 0; j < JN; ++j) {
                const int nb = n0 + wn*WSPAN + j*16 + quad*4;
                const f4 bv = *(const f4*)(bias + nb);
                f4 v = acc[i][j] + bv;
                if (ACT) {
#pragma unroll
                    for (int r = 0; r < 4; ++r) v[r] = gelu_f(v[r]);
                }
                bf4v* cp = (bf4v*)(Cb + m * (size_t)N + nb);
                bf4v o;
                if (OUT == 2) {
                    const bf4v old = *cp;
#pragma unroll
                    for (int r = 0; r < 4; ++r) o[r] = (bf16_t)((float)old[r] + v[r]);
                } else {
#pragma unroll
                    for (int r = 0; r < 4; ++r) o[r] = (bf16_t)v[r];
                }
                *cp = o;
            }
        }
    } else {
        // natural layout: m = ...+quad*4+r (4 consecutive s in Vt), n = ...+l16
#pragma unroll
        for (int j = 0; j < JN; ++j) {
            const int n = n0 + wn*WSPAN + j*16 + l16;
            const float bv = bias[n];
#pragma unroll
            for (int i = 0; i < 4; ++i) {
                const int mbase = m0 + wm*64 + i*16 + quad*4;
                bf4v o;
#pragma unroll
                for (int r = 0; r < 4; ++r) o[r] = (bf16_t)(acc[i][j][r] + bv);
                const size_t b8h = (size_t)((mbase >> 10)*8 + (n >> 6));
                *(bf4v*)(Cb + (b8h*64 + (size_t)(n & 63))*1024 + (mbase & 1023)) = o;
            }
        }
    }
}

template<int BN, int ACT, int OUT>
__global__ __launch_bounds__(256)
void gemm_bt_k(const bf16_t* __restrict__ A, const bf16_t* __restrict__ Bm,
               const float* __restrict__ bias, bf16_t* __restrict__ Cb, int N, int K)
{
    __shared__ __align__(16) bf16_t smem[2*128*64 + 2*BN*64];
    gemm_core<BN, ACT, OUT>(smem, A, Bm, bias, Cb, blockIdx.x * 128, blockIdx.y * BN, N, K);
}

// fused QKV: gridDim.y = 12 (3 mats x 4 n-blocks of 128; V goes to Vt layout).
__global__ __launch_bounds__(256)
void gemm_qkv_k(const bf16_t* __restrict__ A,
                const bf16_t* __restrict__ wq, const bf16_t* __restrict__ wk, const bf16_t* __restrict__ wv,
                const float* __restrict__ bq, const float* __restrict__ bk, const float* __restrict__ bv,
                bf16_t* __restrict__ Q, bf16_t* __restrict__ K, bf16_t* __restrict__ Vt)
{
    __shared__ __align__(16) bf16_t smem[2*128*64 + 2*128*64];
    const int mat = blockIdx.y >> 2;
    const int m0 = blockIdx.x * 128, n0 = (blockIdx.y & 3) * 128;
    if (mat == 0)      gemm_core<128, 0, 1>(smem, A, wq, bq, Q,  m0, n0, NE, NE);
    else if (mat == 1) gemm_core<128, 0, 1>(smem, A, wk, bk, K,  m0, n0, NE, NE);
    else               gemm_core<128, 0, 3>(smem, A, wv, bv, Vt, m0, n0, NE, NE);
}

// ---------------------------------------------------------------------------
// Flash attention (R9 shape — 4 waves x 32 q-rows; R10's 2-wave variant
// regressed: wave-parallelism binds, not LDS dedup). One block = one (b,h)
// x 128 q-rows. K-tile = 64 keys, double-buffered, one barrier/iter.
// No running max (scores O(1); masked keys underflow exp2 to 0).
// grid (64 bh, 8 qb): q-blocks of one bh share an XCD for K/V L2 reuse.
// ---------------------------------------------------------------------------
__global__ __launch_bounds__(256)
void attn_k(const bf16_t* __restrict__ Q, const bf16_t* __restrict__ Kg,
            const bf16_t* __restrict__ Vt, const float* __restrict__ maskf,
            bf16_t* __restrict__ O)
{
    __shared__ __align__(16) bf16_t Ks[2][64*64];  // [key][d]  swizzled
    __shared__ __align__(16) bf16_t Vs[2][64*64];  // [d][key]  swizzled
    __shared__ __align__(16) bf16_t Ps[4][32*64];  // per-wave P, swizzled
    const int tid  = threadIdx.x;
    const int lane = tid & 63;
    const int wave = tid >> 6;
    const int quad = lane >> 4, l16 = lane & 15;
    const int sw = l16 & 7;
    const int bh = blockIdx.x;
    const int b = bh >> 3, h = bh & 7;
    const int q0 = blockIdx.y * 128;

    bf8v qf[2][2];
#pragma unroll
    for (int qi = 0; qi < 2; ++qi) {
        const bf16_t* Qp = Q + (size_t)(b*NS + q0 + wave*32 + qi*16 + l16) * NE + h*ND;
        qf[qi][0] = *(const bf8v*)(Qp + quad*8);
        qf[qi][1] = *(const bf8v*)(Qp + 32 + quad*8);
    }

    f4 oacc[2][4] = {};
    float rs[2] = {0.f, 0.f};

    const int srow = tid >> 3;
    const int scol = (((tid & 7) ^ (srow & 7)) << 3);
    const float c1 = 0.125f * LOG2E;

    auto stage = [&](int buf, int kt) {
#pragma unroll
        for (int r = 0; r < 2; ++r) {
            async_copy16(Kg + (size_t)(b*NS + kt + r*32 + srow) * NE + h*ND + scol,
                         Ks[buf] + (r*256 + tid) * 8);
            async_copy16(Vt + (size_t)(bh*ND + r*32 + srow) * NS + kt + scol,
                         Vs[buf] + (r*256 + tid) * 8);
        }
    };

    stage(0, 0);
    int buf = 0;
    for (int kt = 0; kt < NS; kt += 64, buf ^= 1) {
        __syncthreads();
        if (kt + 64 < NS) stage(buf ^ 1, kt + 64);

        // S = Q*K^T (swapped): sacc[qi][j][r] = S[q=...+l16][key=j*16+quad*4+r]
        f4 sacc[2][4] = {};
#pragma unroll
        for (int j = 0; j < 4; ++j) {
            bf8v kf0 = *(const bf8v*)(Ks[buf] + (j*16 + l16)*64 + ((quad    ) ^ sw)*8);
            bf8v kf1 = *(const bf8v*)(Ks[buf] + (j*16 + l16)*64 + ((quad + 4) ^ sw)*8);
#pragma unroll
            for (int qi = 0; qi < 2; ++qi) {
                sacc[qi][j] = __builtin_amdgcn_mfma_f32_16x16x32_bf16(kf0, qf[qi][0], sacc[qi][j], 0, 0, 0);
                sacc[qi][j] = __builtin_amdgcn_mfma_f32_16x16x32_bf16(kf1, qf[qi][1], sacc[qi][j], 0, 0, 0);
            }
        }

        // P = exp2(S*c1 + mask); packed 8B writes to per-wave LDS (A-layout)
        bf16_t* Pw = Ps[wave];
#pragma unroll
        for (int j = 0; j < 4; ++j) {
            const f4 mkv = *(const f4*)(maskf + b*NS + kt + j*16 + quad*4);
#pragma unroll
            for (int qi = 0; qi < 2; ++qi) {
                bf4v o;
#pragma unroll
                for (int r = 0; r < 4; ++r) {
                    const float p = EXP2F(fmaf(sacc[qi][j][r], c1, mkv[r]));
                    rs[qi] += p;
                    o[r] = (bf16_t)p;
                }
                const int row = qi*16 + l16;
                const int chunk = (j*2 + (quad >> 1)) ^ sw;
                *(bf4v*)(Pw + row*64 + chunk*8 + (quad & 1)*4) = o;
            }
        }

        // O += P*V (swapped): oacc[qi][nt][r] = O[q=l16][d=nt*16+quad*4+r]
#pragma unroll
        for (int ks = 0; ks < 2; ++ks) {
            bf8v pf[2];
#pragma unroll
            for (int qi = 0; qi < 2; ++qi)
                pf[qi] = *(const bf8v*)(Pw + (qi*16 + l16)*64 + ((ks*4 + quad) ^ sw)*8);
#pragma unroll
            for (int nt = 0; nt < 4; ++nt) {
                bf8v vf = *(const bf8v*)(Vs[buf] + (nt*16 + l16)*64 + ((ks*4 + quad) ^ sw)*8);
#pragma unroll
                for (int qi = 0; qi < 2; ++qi)
                    oacc[qi][nt] = __builtin_amdgcn_mfma_f32_16x16x32_bf16(vf, pf[qi], oacc[qi][nt], 0, 0, 0);
            }
        }
    }

    // reduce row sums across quads (scalar per lane), scale, packed stores
#pragma unroll
    for (int qi = 0; qi < 2; ++qi) {
        float s = rs[qi];
        s += __shfl_xor(s, 16, 64);
        s += __shfl_xor(s, 32, 64);
        const float inv = 1.0f / s;
        const size_t row = (size_t)(b*NS + q0 + wave*32 + qi*16 + l16);
#pragma unroll
        for (int nt = 0; nt < 4; ++nt) {
            bf4v o;
#pragma unroll
            for (int r = 0; r < 4; ++r) o[r] = (bf16_t)(oacc[qi][nt][r] * inv);
            *(bf4v*)(O + row * NE + h*ND + nt*16 + quad*4) = o;
        }
    }
}

// ---------------------------------------------------------------------------
// In-place LayerNorm over the bf16 residual stream (residual add already done
// by the producing GEMM's RMW epilogue). Optionally writes fp32 (d_out).
// One block per row; row is fully owned by the block so in-place is safe.
// ---------------------------------------------------------------------------
__global__ __launch_bounds__(256)
void ln_k(bf16_t* __restrict__ xb,
          const float* __restrict__ gamma, const float* __restrict__ beta,
          float* __restrict__ fout, int wf)
{
    const int row = blockIdx.x;
    const int tid = threadIdx.x;
    const size_t base = (size_t)row * NE;
    const float x0 = (float)xb[base + tid];
    const float x1 = (float)xb[base + tid + 256];
    float s  = x0 + x1;
    float ss = x0*x0 + x1*x1;
#pragma unroll
    for (int off = 32; off > 0; off >>= 1) {
        s  += __shfl_down(s,  off, 64);
        ss += __shfl_down(ss, off, 64);
    }
    __shared__ float red[8];
    const int wave = tid >> 6;
    if ((tid & 63) == 0) { red[wave] = s; red[4 + wave] = ss; }
    __syncthreads();
    s  = red[0] + red[1] + red[2] + red[3];
    ss = red[4] + red[5] + red[6] + red[7];
    const float mean = s * (1.0f / NE);
    const float var  = ss * (1.0f / NE) - mean * mean;
    const float inv  = rsqrtf(var + 1e-5f);
    const float o0 = gamma[tid]       * ((x0 - mean) * inv) + beta[tid];
    const float o1 = gamma[tid + 256] * ((x1 - mean) * inv) + beta[tid + 256];
    xb[base + tid]       = (bf16_t)o0;
    xb[base + tid + 256] = (bf16_t)o1;
    if (wf) {
        fout[base + tid]       = o0;
        fout[base + tid + 256] = o1;
    }
}

// one-shot fp32->bf16 conversion of all 6 weight tensors + x (single launch)
#define W4SZ ((size_t)NL*NE*NE/4)     // float4s per E x E weight set
#define WBSZ ((size_t)NL*NE*NHF/4)    // float4s per E x HF weight set
#define XSZ  ((size_t)NROW*NE/4)      // float4s for x
#define CVT_TOTAL (4*W4SZ + 2*WBSZ + XSZ)

__global__ void cvt_all(const float* __restrict__ wq, const float* __restrict__ wk,
                        const float* __restrict__ wv, const float* __restrict__ wo,
                        const float* __restrict__ w1, const float* __restrict__ w2,
                        const float* __restrict__ x,
                        bf16_t* __restrict__ owq, bf16_t* __restrict__ owk,
                        bf16_t* __restrict__ owv, bf16_t* __restrict__ owo,
                        bf16_t* __restrict__ ow1, bf16_t* __restrict__ ow2,
                        bf16_t* __restrict__ ox)
{
    size_t i = (size_t)blockIdx.x * 256 + threadIdx.x;
    if (i >= CVT_TOTAL) return;
    const float* src; bf16_t* dst;
    if      (i < 1*W4SZ)           { src = wq; dst = owq; }
    else if (i < 2*W4SZ)           { src = wk; dst = owk; i -= 1*W4SZ; }
    else if (i < 3*W4SZ)           { src = wv; dst = owv; i -= 2*W4SZ; }
    else if (i < 4*W4SZ)           { src = wo; dst = owo; i -= 3*W4SZ; }
    else if (i < 4*W4SZ + WBSZ)    { src = w1; dst = ow1; i -= 4*W4SZ; }
    else if (i < 4*W4SZ + 2*WBSZ)  { src = w2; dst = ow2; i -= 4*W4SZ + WBSZ; }
    else                           { src = x;  dst = ox;  i -= 4*W4SZ + 2*WBSZ; }
    const f4 v = ((const f4*)src)[i];
    bf4v o;
    o[0] = (bf16_t)v[0]; o[1] = (bf16_t)v[1]; o[2] = (bf16_t)v[2]; o[3] = (bf16_t)v[3];
    ((bf4v*)dst)[i] = o;
}

__global__ void make_maskf(const int* __restrict__ m, float* __restrict__ out, int n)
{
    const int i = blockIdx.x * 256 + threadIdx.x;
    if (i < n) out[i] = m[i] ? 0.0f : -1.0e6f * LOG2E;  // exp2-domain mask
}

// ---------------------------------------------------------------------------
extern "C" void kernel_launch(void* const* d_in, const int* in_sizes, int n_in,
                              void* d_out, int out_size, void* d_ws, size_t ws_size,
                              hipStream_t stream)
{
    (void)in_sizes; (void)n_in; (void)out_size; (void)ws_size;
    const float* x   = (const float*)d_in[0];
    const int*   msk = (const int*)d_in[1];
    const float* WQ = (const float*)d_in[2];  const float* bQ  = (const float*)d_in[3];
    const float* WK = (const float*)d_in[4];  const float* bK  = (const float*)d_in[5];
    const float* WV = (const float*)d_in[6];  const float* bV  = (const float*)d_in[7];
    const float* WO = (const float*)d_in[8];  const float* bO  = (const float*)d_in[9];
    const float* W1 = (const float*)d_in[10]; const float* b1  = (const float*)d_in[11];
    const float* W2 = (const float*)d_in[12]; const float* b2  = (const float*)d_in[13];
    const float* g1 = (const float*)d_in[14]; const float* bt1 = (const float*)d_in[15];
    const float* g2 = (const float*)d_in[16]; const float* bt2 = (const float*)d_in[17];

    char* ws = (char*)d_ws;
    size_t off = 0;
    auto alloc = [&](size_t bytes) { char* p = ws + off; off += (bytes + 255) & ~(size_t)255; return p; };
    bf16_t* xb    = (bf16_t*)alloc((size_t)NROW*NE*2);
    bf16_t* Qb    = (bf16_t*)alloc((size_t)NROW*NE*2);
    bf16_t* Kb    = (bf16_t*)alloc((size_t)NROW*NE*2);
    bf16_t* Vtb   = (bf16_t*)alloc((size_t)NROW*NE*2);
    bf16_t* AOb   = (bf16_t*)alloc((size_t)NROW*NE*2);
    bf16_t* hb    = (bf16_t*)alloc((size_t)NROW*NHF*2);
    bf16_t* wqc   = (bf16_t*)alloc((size_t)NL*NE*NE*2);
    bf16_t* wkc   = (bf16_t*)alloc((size_t)NL*NE*NE*2);
    bf16_t* wvc   = (bf16_t*)alloc((size_t)NL*NE*NE*2);
    bf16_t* woc   = (bf16_t*)alloc((size_t)NL*NE*NE*2);
    bf16_t* w1c   = (bf16_t*)alloc((size_t)NL*NHF*NE*2);
    bf16_t* w2c   = (bf16_t*)alloc((size_t)NL*NE*NHF*2);
    float*  maskf = (float*) alloc((size_t)NB*NS*4);

    cvt_all<<<dim3((unsigned)((CVT_TOTAL + 255) / 256)), dim3(256), 0, stream>>>(
        WQ, WK, WV, WO, W1, W2, x, wqc, wkc, wvc, woc, w1c, w2c, xb);
    make_maskf<<<dim3(32), dim3(256), 0, stream>>>(msk, maskf, NB*NS);

    for (int l = 0; l < NL; ++l) {
        const bf16_t* wq  = wqc + (size_t)l*NE*NE;
        const bf16_t* wk  = wkc + (size_t)l*NE*NE;
        const bf16_t* wv  = wvc + (size_t)l*NE*NE;
        const bf16_t* wo  = woc + (size_t)l*NE*NE;
        const bf16_t* w1p = w1c + (size_t)l*NHF*NE;
        const bf16_t* w2p = w2c + (size_t)l*NE*NHF;

        gemm_qkv_k<<<dim3(64, 12), dim3(256), 0, stream>>>(
            xb, wq, wk, wv, bQ + l*NE, bK + l*NE, bV + l*NE, Qb, Kb, Vtb);
        attn_k<<<dim3(64, 8), dim3(256), 0, stream>>>(Qb, Kb, Vtb, maskf, AOb);
        gemm_bt_k<64, 0, 2><<<dim3(64, 8), dim3(256), 0, stream>>>(
            AOb, wo, bO + l*NE, xb, NE, NE);              // xb += O-proj
        ln_k<<<dim3(NROW), dim3(256), 0, stream>>>(
            xb, g1 + l*NE, bt1 + l*NE, nullptr, 0);       // xb = LN(xb)
        gemm_bt_k<128, 1, 1><<<dim3(64, 16), dim3(256), 0, stream>>>(
            xb, w1p, b1 + l*NHF, hb, NHF, NE);
        gemm_bt_k<64, 0, 2><<<dim3(64, 8), dim3(256), 0, stream>>>(
            hb, w2p, b2 + l*NE, xb, NE, NHF);             // xb += FFN2
        const int last = (l == NL - 1);
        ln_k<<<dim3(NROW), dim3(256), 0, stream>>>(
            xb, g2 + l*NE, bt2 + l*NE, (float*)d_out, last);
    }
}

// Round 12
// 927.989 us; speedup vs baseline: 1.1613x; 1.0429x over previous
//
#include <hip/hip_runtime.h>
#include <cstdint>
#include <cstddef>

#define NB 8
#define NS 1024
#define NE 512
#define NH 8
#define ND 64
#define NL 6
#define NHF 2048
#define NROW (NB*NS)   // 8192

typedef __bf16 bf16_t;
typedef __bf16 bf8v __attribute__((ext_vector_type(8)));
typedef __bf16 bf4v __attribute__((ext_vector_type(4)));
typedef float  f4   __attribute__((ext_vector_type(4)));

extern "C" __device__ float __ocml_native_exp2_f32(float);
#define EXP2F __ocml_native_exp2_f32
#define LOG2E 1.4426950408889634f

// ---- async global->LDS, 16B per lane (LDS dest = wave-uniform base + lane*16) ----
__device__ __forceinline__ void async_copy16(const bf16_t* g, bf16_t* l) {
    __builtin_amdgcn_global_load_lds(
        (const __attribute__((address_space(1))) void*)g,
        (__attribute__((address_space(3))) void*)l,
        16, 0, 0);
}

// gelu(x) = x * sigmoid(2*0.7978845608*(x+0.044715x^3)); exp2-domain, v_rcp.
__device__ __forceinline__ float gelu_f(float x) {
    const float s = fmaf(0.044715f * x * x, x, x);
    const float e = EXP2F(-2.3022081995f * s);   // 2*0.7978845608*log2(e)
    return x * __builtin_amdgcn_rcpf(1.0f + e);
}

// ---------------------------------------------------------------------------
// Core bf16 GEMM: C[M,N] = A[M,K] * B[N,K]^T (+bias, opt gelu)
// OUT: 1 = bf16 row-major (swapped mfma -> 8B stores)
//      2 = bf16 in-place residual RMW (swapped)
//      4 = bf16 row-major with PACKED row remap: row = (m&~1023)+rank[m]
//      5 = bf16 scattered into packed Vt[(b*8+h)*64+d][rank[s]] (natural mfma)
// 128xBN tile, BK=64, 256 threads, XOR-8 LDS swizzle (conflict-free).
// A and B staged via global_load_lds, DOUBLE-BUFFERED, one barrier/k-iter.
// ---------------------------------------------------------------------------
template<int BN, int ACT, int OUT>
__device__ __forceinline__ void gemm_core(
    bf16_t* __restrict__ sm,
    const bf16_t* __restrict__ A, const bf16_t* __restrict__ Bm,
    const float* __restrict__ bias, bf16_t* __restrict__ Cb,
    const unsigned short* __restrict__ rank,
    int m0, int n0, int N, int K)
{
    constexpr int JN = BN / 32, WSPAN = BN / 2;
    bf16_t* As = sm;             // 2 x 8192
    bf16_t* Bs = sm + 2*128*64;  // 2 x (BN*64)
    const int tid  = threadIdx.x;
    const int lane = tid & 63;
    const int wave = tid >> 6;
    const int wm = wave >> 1, wn = wave & 1;
    const int quad = lane >> 4, l16 = lane & 15;
    const int srow = tid >> 3;                         // 0..31
    const int scol = (((tid & 7) ^ (srow & 7)) << 3);  // swizzled source col

    f4 acc[4][JN] = {};

    const bf16_t* Ag = A  + (size_t)(m0 + srow) * K + scol;
    const bf16_t* Bg = Bm + (size_t)(n0 + srow) * K + scol;
    const int sw = (l16 & 7);

    auto stage = [&](int buf, int kt) {
#pragma unroll
        for (int r = 0; r < 4; ++r)
            async_copy16(Ag + (size_t)r * 32 * K + kt, As + buf*8192 + tid*8 + r*2048);
#pragma unroll
        for (int r = 0; r < BN/32; ++r)
            async_copy16(Bg + (size_t)r * 32 * K + kt, Bs + buf*(BN*64) + tid*8 + r*2048);
    };

    stage(0, 0);
    int buf = 0;
    for (int kt = 0; kt < K; kt += 64, buf ^= 1) {
        __syncthreads();                       // drains buf's loads; frees buf^1
        if (kt + 64 < K) stage(buf ^ 1, kt + 64);
        const bf16_t* Ab = As + buf*8192;
        const bf16_t* Bb = Bs + buf*(BN*64);
#pragma unroll
        for (int s = 0; s < 2; ++s) {
            const int c8 = ((s*4 + quad) ^ sw) * 8;
            bf8v af[4], bfv[JN];
#pragma unroll
            for (int i = 0; i < 4; ++i)
                af[i] = *(const bf8v*)(Ab + (wm*64 + i*16 + l16)*64 + c8);
#pragma unroll
            for (int j = 0; j < JN; ++j)
                bfv[j] = *(const bf8v*)(Bb + (wn*WSPAN + j*16 + l16)*64 + c8);
#pragma unroll
            for (int i = 0; i < 4; ++i)
#pragma unroll
                for (int j = 0; j < JN; ++j) {
                    if (OUT == 5)
                        acc[i][j] = __builtin_amdgcn_mfma_f32_16x16x32_bf16(af[i], bfv[j], acc[i][j], 0, 0, 0);
                    else
                        acc[i][j] = __builtin_amdgcn_mfma_f32_16x16x32_bf16(bfv[j], af[i], acc[i][j], 0, 0, 0);
                }
        }
    }

    if (OUT != 5) {
        // swapped layout: m = ...+l16, n = ...+quad*4+r (4 consecutive n/lane)
#pragma unroll
        for (int i = 0; i < 4; ++i) {
            const int mi = m0 + wm*64 + i*16 + l16;
            size_t m = (size_t)mi;
            if (OUT == 4) m = (size_t)((mi & ~1023) + (int)rank[mi]);
#pragma unroll
            for (int j = 0; j < JN; ++j) {
                const int nb = n0 + wn*WSPAN + j*16 + quad*4;
                const f4 bv = *(const f4*)(bias + nb);
                f4 v = acc[i][j] + bv;
                if (ACT) {
#pragma unroll
                    for (int r = 0; r < 4; ++r) v[r] = gelu_f(v[r]);
                }
                bf4v* cp = (bf4v*)(Cb + m * (size_t)N + nb);
                bf4v o;
                if (OUT == 2) {
                    const bf4v old = *cp;
#pragma unroll
                    for (int r = 0; r < 4; ++r) o[r] = (bf16_t)((float)old[r] + v[r]);
                } else {
#pragma unroll
                    for (int r = 0; r < 4; ++r) o[r] = (bf16_t)v[r];
                }
                *cp = o;
            }
        }
    } else {
        // natural layout: m = ...+quad*4+r (s dim), n = ...+l16 (d dim);
        // packed column scatter: col = rank[s]
#pragma unroll
        for (int j = 0; j < JN; ++j) {
            const int n = n0 + wn*WSPAN + j*16 + l16;
            const float bv = bias[n];
#pragma unroll
            for (int i = 0; i < 4; ++i) {
                const int mbase = m0 + wm*64 + i*16 + quad*4;
                const size_t b8h = (size_t)((mbase >> 10)*8 + (n >> 6));
                bf16_t* rowp = Cb + (b8h*64 + (size_t)(n & 63))*1024;
#pragma unroll
                for (int r = 0; r < 4; ++r)
                    rowp[rank[mbase + r]] = (bf16_t)(acc[i][j][r] + bv);
            }
        }
    }
}

template<int BN, int ACT, int OUT>
__global__ __launch_bounds__(256)
void gemm_bt_k(const bf16_t* __restrict__ A, const bf16_t* __restrict__ Bm,
               const float* __restrict__ bias, bf16_t* __restrict__ Cb, int N, int K)
{
    __shared__ __align__(16) bf16_t smem[2*128*64 + 2*BN*64];
    gemm_core<BN, ACT, OUT>(smem, A, Bm, bias, Cb, nullptr,
                            blockIdx.x * 128, blockIdx.y * BN, N, K);
}

// fused QKV: gridDim.y = 12 (Q row-major; K packed-row; V packed-Vt scatter).
__global__ __launch_bounds__(256)
void gemm_qkv_k(const bf16_t* __restrict__ A,
                const bf16_t* __restrict__ wq, const bf16_t* __restrict__ wk, const bf16_t* __restrict__ wv,
                const float* __restrict__ bq, const float* __restrict__ bk, const float* __restrict__ bv,
                bf16_t* __restrict__ Q, bf16_t* __restrict__ K, bf16_t* __restrict__ Vt,
                const unsigned short* __restrict__ rank)
{
    __shared__ __align__(16) bf16_t smem[2*128*64 + 2*128*64];
    const int mat = blockIdx.y >> 2;
    const int m0 = blockIdx.x * 128, n0 = (blockIdx.y & 3) * 128;
    if (mat == 0)      gemm_core<128, 0, 1>(smem, A, wq, bq, Q,  nullptr, m0, n0, NE, NE);
    else if (mat == 1) gemm_core<128, 0, 4>(smem, A, wk, bk, K,  rank,    m0, n0, NE, NE);
    else               gemm_core<128, 0, 5>(smem, A, wv, bv, Vt, rank,    m0, n0, NE, NE);
}

// ---------------------------------------------------------------------------
// Mask packing (once per call): per batch b, rank[s] = position among
// unmasked keys (or cnt + position among masked -> tail), cntpad[b] =
// ceil(cnt/64)*64, maskp[j] = 0 for j<cnt else -inf (exp2 domain).
// Skipping masked keys is exact: their P entries are exp2(-1.4e6) = 0.
// One wave per batch; ballot/popcount scan over 16 chunks of 64.
// ---------------------------------------------------------------------------
__global__ __launch_bounds__(64)
void pack_k(const int* __restrict__ m, unsigned short* __restrict__ rank,
            int* __restrict__ cntpad, float* __restrict__ maskp)
{
    const int b = blockIdx.x, lane = threadIdx.x;
    unsigned long long bals[16];
    int cnt = 0;
#pragma unroll
    for (int c = 0; c < 16; ++c) {
        const bool mk = m[b*NS + c*64 + lane] != 0;
        bals[c] = __ballot(mk);
        cnt += __popcll(bals[c]);
    }
    int u = 0, kk = 0;
#pragma unroll
    for (int c = 0; c < 16; ++c) {
        const unsigned long long bal = bals[c];
        const bool mk = (bal >> lane) & 1;
        const int pu = __popcll(bal & ((1ull << lane) - 1));
        const int r = mk ? (u + pu) : (cnt + kk + (lane - pu));
        rank[b*NS + c*64 + lane] = (unsigned short)r;
        const int cb = __popcll(bal);
        u += cb; kk += 64 - cb;
    }
    if (lane == 0) {
        int cp = (cnt + 63) & ~63;
        cntpad[b] = cp < 64 ? 64 : cp;
    }
#pragma unroll
    for (int c = 0; c < 16; ++c) {
        const int j = c*64 + lane;
        maskp[b*NS + j] = (j < cnt) ? 0.0f : -1.0e6f * LOG2E;
    }
}

// ---------------------------------------------------------------------------
// Flash attention over PACKED keys: K rows / Vt cols are pre-permuted so the
// first cnt[b] positions are the unmasked keys; loop runs to cntpad[b]
// (~half of NS on this mask distribution) — exact math, zero terms skipped.
// 4 waves x 32 q-rows (R10 showed 2-wave blocks regress: wave-parallelism
// binds). K-tile = 64 keys, double-buffered, one barrier/iter.
// grid (64 bh, 8 qb): q-blocks of one bh share an XCD for K/V L2 reuse.
// ---------------------------------------------------------------------------
__global__ __launch_bounds__(256)
void attn_k(const bf16_t* __restrict__ Q, const bf16_t* __restrict__ Kg,
            const bf16_t* __restrict__ Vt, const float* __restrict__ maskf,
            const int* __restrict__ cntpad, bf16_t* __restrict__ O)
{
    __shared__ __align__(16) bf16_t Ks[2][64*64];  // [key][d]  swizzled
    __shared__ __align__(16) bf16_t Vs[2][64*64];  // [d][key]  swizzled
    __shared__ __align__(16) bf16_t Ps[4][32*64];  // per-wave P, swizzled
    const int tid  = threadIdx.x;
    const int lane = tid & 63;
    const int wave = tid >> 6;
    const int quad = lane >> 4, l16 = lane & 15;
    const int sw = l16 & 7;
    const int bh = blockIdx.x;
    const int b = bh >> 3, h = bh & 7;
    const int q0 = blockIdx.y * 128;
    const int kend = cntpad[b];

    bf8v qf[2][2];
#pragma unroll
    for (int qi = 0; qi < 2; ++qi) {
        const bf16_t* Qp = Q + (size_t)(b*NS + q0 + wave*32 + qi*16 + l16) * NE + h*ND;
        qf[qi][0] = *(const bf8v*)(Qp + quad*8);
        qf[qi][1] = *(const bf8v*)(Qp + 32 + quad*8);
    }

    f4 oacc[2][4] = {};
    float rs[2] = {0.f, 0.f};

    const int srow = tid >> 3;
    const int scol = (((tid & 7) ^ (srow & 7)) << 3);
    const float c1 = 0.125f * LOG2E;

    auto stage = [&](int buf, int kt) {
#pragma unroll
        for (int r = 0; r < 2; ++r) {
            async_copy16(Kg + (size_t)(b*NS + kt + r*32 + srow) * NE + h*ND + scol,
                         Ks[buf] + (r*256 + tid) * 8);
            async_copy16(Vt + (size_t)(bh*ND + r*32 + srow) * NS + kt + scol,
                         Vs[buf] + (r*256 + tid) * 8);
        }
    };

    stage(0, 0);
    int buf = 0;
    for (int kt = 0; kt < kend; kt += 64, buf ^= 1) {
        __syncthreads();
        if (kt + 64 < kend) stage(buf ^ 1, kt + 64);

        // S = Q*K^T (swapped): sacc[qi][j][r] = S[q=...+l16][key=j*16+quad*4+r]
        f4 sacc[2][4] = {};
#pragma unroll
        for (int j = 0; j < 4; ++j) {
            bf8v kf0 = *(const bf8v*)(Ks[buf] + (j*16 + l16)*64 + ((quad    ) ^ sw)*8);
            bf8v kf1 = *(const bf8v*)(Ks[buf] + (j*16 + l16)*64 + ((quad + 4) ^ sw)*8);
#pragma unroll
            for (int qi = 0; qi < 2; ++qi) {
                sacc[qi][j] = __builtin_amdgcn_mfma_f32_16x16x32_bf16(kf0, qf[qi][0], sacc[qi][j], 0, 0, 0);
                sacc[qi][j] = __builtin_amdgcn_mfma_f32_16x16x32_bf16(kf1, qf[qi][1], sacc[qi][j], 0, 0, 0);
            }
        }

        // P = exp2(S*c1 + mask); packed 8B writes to per-wave LDS (A-layout)
        bf16_t* Pw = Ps[wave];
#pragma unroll
        for (int j = 0; j < 4; ++j) {
            const f4 mkv = *(const f4*)(maskf + b*NS + kt + j*16 + quad*4);
#pragma unroll
            for (int qi = 0; qi < 2; ++qi) {
                bf4v o;
#pragma unroll
                for (int r = 0; r < 4; ++r) {
                    const float p = EXP2F(fmaf(sacc[qi][j][r], c1, mkv[r]));
                    rs[qi] += p;
                    o[r] = (bf16_t)p;
                }
                const int row = qi*16 + l16;
                const int chunk = (j*2 + (quad >> 1)) ^ sw;
                *(bf4v*)(Pw + row*64 + chunk*8 + (quad & 1)*4) = o;
            }
        }

        // O += P*V (swapped): oacc[qi][nt][r] = O[q=l16][d=nt*16+quad*4+r]
#pragma unroll
        for (int ks = 0; ks < 2; ++ks) {
            bf8v pf[2];
#pragma unroll
            for (int qi = 0; qi < 2; ++qi)
                pf[qi] = *(const bf8v*)(Pw + (qi*16 + l16)*64 + ((ks*4 + quad) ^ sw)*8);
#pragma unroll
            for (int nt = 0; nt < 4; ++nt) {
                bf8v vf = *(const bf8v*)(Vs[buf] + (nt*16 + l16)*64 + ((ks*4 + quad) ^ sw)*8);
#pragma unroll
                for (int qi = 0; qi < 2; ++qi)
                    oacc[qi][nt] = __builtin_amdgcn_mfma_f32_16x16x32_bf16(vf, pf[qi], oacc[qi][nt], 0, 0, 0);
            }
        }
    }

    // reduce row sums across quads (scalar per lane), scale, packed stores
#pragma unroll
    for (int qi = 0; qi < 2; ++qi) {
        float s = rs[qi];
        s += __shfl_xor(s, 16, 64);
        s += __shfl_xor(s, 32, 64);
        const float inv = 1.0f / s;
        const size_t row = (size_t)(b*NS + q0 + wave*32 + qi*16 + l16);
#pragma unroll
        for (int nt = 0; nt < 4; ++nt) {
            bf4v o;
#pragma unroll
            for (int r = 0; r < 4; ++r) o[r] = (bf16_t)(oacc[qi][nt][r] * inv);
            *(bf4v*)(O + row * NE + h*ND + nt*16 + quad*4) = o;
        }
    }
}

// ---------------------------------------------------------------------------
// In-place LayerNorm over the bf16 residual stream (residual add already done
// by the producing GEMM's RMW epilogue). Optionally writes fp32 (d_out).
// ---------------------------------------------------------------------------
__global__ __launch_bounds__(256)
void ln_k(bf16_t* __restrict__ xb,
          const float* __restrict__ gamma, const float* __restrict__ beta,
          float* __restrict__ fout, int wf)
{
    const int row = blockIdx.x;
    const int tid = threadIdx.x;
    const size_t base = (size_t)row * NE;
    const float x0 = (float)xb[base + tid];
    const float x1 = (float)xb[base + tid + 256];
    float s  = x0 + x1;
    float ss = x0*x0 + x1*x1;
#pragma unroll
    for (int off = 32; off > 0; off >>= 1) {
        s  += __shfl_down(s,  off, 64);
        ss += __shfl_down(ss, off, 64);
    }
    __shared__ float red[8];
    const int wave = tid >> 6;
    if ((tid & 63) == 0) { red[wave] = s; red[4 + wave] = ss; }
    __syncthreads();
    s  = red[0] + red[1] + red[2] + red[3];
    ss = red[4] + red[5] + red[6] + red[7];
    const float mean = s * (1.0f / NE);
    const float var  = ss * (1.0f / NE) - mean * mean;
    const float inv  = rsqrtf(var + 1e-5f);
    const float o0 = gamma[tid]       * ((x0 - mean) * inv) + beta[tid];
    const float o1 = gamma[tid + 256] * ((x1 - mean) * inv) + beta[tid + 256];
    xb[base + tid]       = (bf16_t)o0;
    xb[base + tid + 256] = (bf16_t)o1;
    if (wf) {
        fout[base + tid]       = o0;
        fout[base + tid + 256] = o1;
    }
}

// one-shot fp32->bf16 conversion of all 6 weight tensors + x (single launch)
#define W4SZ ((size_t)NL*NE*NE/4)     // float4s per E x E weight set
#define WBSZ ((size_t)NL*NE*NHF/4)    // float4s per E x HF weight set
#define XSZ  ((size_t)NROW*NE/4)      // float4s for x
#define CVT_TOTAL (4*W4SZ + 2*WBSZ + XSZ)

__global__ void cvt_all(const float* __restrict__ wq, const float* __restrict__ wk,
                        const float* __restrict__ wv, const float* __restrict__ wo,
                        const float* __restrict__ w1, const float* __restrict__ w2,
                        const float* __restrict__ x,
                        bf16_t* __restrict__ owq, bf16_t* __restrict__ owk,
                        bf16_t* __restrict__ owv, bf16_t* __restrict__ owo,
                        bf16_t* __restrict__ ow1, bf16_t* __restrict__ ow2,
                        bf16_t* __restrict__ ox)
{
    size_t i = (size_t)blockIdx.x * 256 + threadIdx.x;
    if (i >= CVT_TOTAL) return;
    const float* src; bf16_t* dst;
    if      (i < 1*W4SZ)           { src = wq; dst = owq; }
    else if (i < 2*W4SZ)           { src = wk; dst = owk; i -= 1*W4SZ; }
    else if (i < 3*W4SZ)           { src = wv; dst = owv; i -= 2*W4SZ; }
    else if (i < 4*W4SZ)           { src = wo; dst = owo; i -= 3*W4SZ; }
    else if (i < 4*W4SZ + WBSZ)    { src = w1; dst = ow1; i -= 4*W4SZ; }
    else if (i < 4*W4SZ + 2*WBSZ)  { src = w2; dst = ow2; i -= 4*W4SZ + WBSZ; }
    else                           { src = x;  dst = ox;  i -= 4*W4SZ + 2*WBSZ; }
    const f4 v = ((const f4*)src)[i];
    bf4v o;
    o[0] = (bf16_t)v[0]; o[1] = (bf16_t)v[1]; o[2] = (bf16_t)v[2]; o[3] = (bf16_t)v[3];
    ((bf4v*)dst)[i] = o;
}

// ---------------------------------------------------------------------------
extern "C" void kernel_launch(void* const* d_in, const int* in_sizes, int n_in,
                              void* d_out, int out_size, void* d_ws, size_t ws_size,
                              hipStream_t stream)
{
    (void)in_sizes; (void)n_in; (void)out_size; (void)ws_size;
    const float* x   = (const float*)d_in[0];
    const int*   msk = (const int*)d_in[1];
    const float* WQ = (const float*)d_in[2];  const float* bQ  = (const float*)d_in[3];
    const float* WK = (const float*)d_in[4];  const float* bK  = (const float*)d_in[5];
    const float* WV = (const float*)d_in[6];  const float* bV  = (const float*)d_in[7];
    const float* WO = (const float*)d_in[8];  const float* bO  = (const float*)d_in[9];
    const float* W1 = (const float*)d_in[10]; const float* b1  = (const float*)d_in[11];
    const float* W2 = (const float*)d_in[12]; const float* b2  = (const float*)d_in[13];
    const float* g1 = (const float*)d_in[14]; const float* bt1 = (const float*)d_in[15];
    const float* g2 = (const float*)d_in[16]; const float* bt2 = (const float*)d_in[17];

    char* ws = (char*)d_ws;
    size_t off = 0;
    auto alloc = [&](size_t bytes) { char* p = ws + off; off += (bytes + 255) & ~(size_t)255; return p; };
    bf16_t* xb    = (bf16_t*)alloc((size_t)NROW*NE*2);
    bf16_t* Qb    = (bf16_t*)alloc((size_t)NROW*NE*2);
    bf16_t* Kb    = (bf16_t*)alloc((size_t)NROW*NE*2);
    bf16_t* Vtb   = (bf16_t*)alloc((size_t)NROW*NE*2);
    bf16_t* AOb   = (bf16_t*)alloc((size_t)NROW*NE*2);
    bf16_t* hb    = (bf16_t*)alloc((size_t)NROW*NHF*2);
    bf16_t* wqc   = (bf16_t*)alloc((size_t)NL*NE*NE*2);
    bf16_t* wkc   = (bf16_t*)alloc((size_t)NL*NE*NE*2);
    bf16_t* wvc   = (bf16_t*)alloc((size_t)NL*NE*NE*2);
    bf16_t* woc   = (bf16_t*)alloc((size_t)NL*NE*NE*2);
    bf16_t* w1c   = (bf16_t*)alloc((size_t)NL*NHF*NE*2);
    bf16_t* w2c   = (bf16_t*)alloc((size_t)NL*NE*NHF*2);
    float*  maskp = (float*) alloc((size_t)NB*NS*4);
    unsigned short* rankb = (unsigned short*)alloc((size_t)NB*NS*2);
    int*    cntp  = (int*)   alloc(NB*4);

    cvt_all<<<dim3((unsigned)((CVT_TOTAL + 255) / 256)), dim3(256), 0, stream>>>(
        WQ, WK, WV, WO, W1, W2, x, wqc, wkc, wvc, woc, w1c, w2c, xb);
    pack_k<<<dim3(NB), dim3(64), 0, stream>>>(msk, rankb, cntp, maskp);

    for (int l = 0; l < NL; ++l) {
        const bf16_t* wq  = wqc + (size_t)l*NE*NE;
        const bf16_t* wk  = wkc + (size_t)l*NE*NE;
        const bf16_t* wv  = wvc + (size_t)l*NE*NE;
        const bf16_t* wo  = woc + (size_t)l*NE*NE;
        const bf16_t* w1p = w1c + (size_t)l*NHF*NE;
        const bf16_t* w2p = w2c + (size_t)l*NE*NHF;

        gemm_qkv_k<<<dim3(64, 12), dim3(256), 0, stream>>>(
            xb, wq, wk, wv, bQ + l*NE, bK + l*NE, bV + l*NE, Qb, Kb, Vtb, rankb);
        attn_k<<<dim3(64, 8), dim3(256), 0, stream>>>(Qb, Kb, Vtb, maskp, cntp, AOb);
        gemm_bt_k<64, 0, 2><<<dim3(64, 8), dim3(256), 0, stream>>>(
            AOb, wo, bO + l*NE, xb, NE, NE);              // xb += O-proj
        ln_k<<<dim3(NROW), dim3(256), 0, stream>>>(
            xb, g1 + l*NE, bt1 + l*NE, nullptr, 0);       // xb = LN(xb)
        gemm_bt_k<128, 1, 1><<<dim3(64, 16), dim3(256), 0, stream>>>(
            xb, w1p, b1 + l*NHF, hb, NHF, NE);
        gemm_bt_k<64, 0, 2><<<dim3(64, 8), dim3(256), 0, stream>>>(
            hb, w2p, b2 + l*NE, xb, NE, NHF);             // xb += FFN2
        const int last = (l == NL - 1);
        ln_k<<<dim3(NROW), dim3(256), 0, stream>>>(
            xb, g2 + l*NE, bt2 + l*NE, (float*)d_out, last);
    }
}